// Round 5
// baseline (122.511 us; speedup 1.0000x reference)
//
#include <hip/hip_runtime.h>

#define BB 2
#define SDIM 1024
#define DDIM 128
#define K1_ROWS 4

#define F4GET(v,k) ((k)==0?(v).x:((k)==1?(v).y:((k)==2?(v).z:(v).w)))

typedef float f2 __attribute__((ext_vector_type(2)));

// ---------------- Kernel 1: projections + row dot products ----------------
// hi[n][d]  = sum_k x[n][k] * W1[k][d]
// hjb[n][d] = sum_k x[n][k] * W1[D+k][d] + b1[d]
// si2[n] = 0.5*(hi[n].w2) ; sj2[n] = 0.5*(hjb[n].w2) + b2 ; w2h[d] = 0.5*w2[d]
__global__ __launch_bounds__(256) void proj_kernel(
    const float* __restrict__ x, const float* __restrict__ W1,
    const float* __restrict__ b1, const float* __restrict__ W2,
    const float* __restrict__ b2,
    float* __restrict__ hi, float* __restrict__ hjb,
    float* __restrict__ si2, float* __restrict__ sj2, float* __restrict__ w2h)
{
    __shared__ float sX[K1_ROWS][DDIM];
    __shared__ float sRed[4][K1_ROWS];
    const int tid  = threadIdx.x;
    const int d    = tid & 127;
    const int half = tid >> 7;
    const int r0   = blockIdx.x * K1_ROWS;

    if (tid < K1_ROWS * DDIM / 4) {
        reinterpret_cast<float4*>(&sX[0][0])[tid] =
            reinterpret_cast<const float4*>(x + (size_t)r0 * DDIM)[tid];
    }
    __syncthreads();

    const float* Wh = W1 + (size_t)half * DDIM * DDIM;

    float acc[K1_ROWS];
    #pragma unroll
    for (int r = 0; r < K1_ROWS; ++r) acc[r] = 0.f;

    #pragma unroll 4
    for (int k = 0; k < DDIM; k += 4) {
        float4 xv[K1_ROWS];
        #pragma unroll
        for (int r = 0; r < K1_ROWS; ++r)
            xv[r] = *reinterpret_cast<const float4*>(&sX[r][k]);
        #pragma unroll
        for (int kk = 0; kk < 4; ++kk) {
            float w = Wh[(size_t)(k + kk) * DDIM + d];
            #pragma unroll
            for (int r = 0; r < K1_ROWS; ++r)
                acc[r] = fmaf(F4GET(xv[r], kk), w, acc[r]);
        }
    }

    if (half) {
        const float bv = b1[d];
        #pragma unroll
        for (int r = 0; r < K1_ROWS; ++r) acc[r] += bv;
    }

    float* hout = half ? hjb : hi;
    #pragma unroll
    for (int r = 0; r < K1_ROWS; ++r)
        hout[(size_t)(r0 + r) * DDIM + d] = acc[r];

    const float wv   = W2[d];
    if (!half) w2h[d] = 0.5f * wv;   // idempotent across blocks
    const int   lane = tid & 63;
    const int   wave = tid >> 6;
    #pragma unroll
    for (int r = 0; r < K1_ROWS; ++r) {
        float v = acc[r] * wv;
        #pragma unroll
        for (int off = 32; off >= 1; off >>= 1)
            v += __shfl_xor(v, off, 64);
        if (lane == 0) sRed[wave][r] = v;
    }
    __syncthreads();
    if (tid < K1_ROWS) {
        si2[r0 + tid] = 0.5f * (sRed[0][tid] + sRed[1][tid]);
    } else if (tid < 2 * K1_ROWS) {
        int r = tid - K1_ROWS;
        sj2[r0 + r] = 0.5f * (sRed[2][r] + sRed[3][r]) + b2[0];
    }
}

// ---------------- Kernel 2: pairwise edge logits (register-resident A) ----
// out[b,i,j] = si2[b,i] + sj2[b,j] + sum_d |hi[b,i,d] + hjb[b,j,d]| * w2h[d]
// lane -> i-row (A row in 128 VGPRs, static indexing). Wave walks 8 j's.
// B and W rows are wave-uniform -> same-address global broadcast loads (L1,
// VMEM pipe). No LDS, no barriers. 1.5 VALU insts per (pair,d).
__global__ __launch_bounds__(256, 2) void edge_kernel(
    const float* __restrict__ hi, const float* __restrict__ hjb,
    const float* __restrict__ si2, const float* __restrict__ sj2,
    const float* __restrict__ w2h, float* __restrict__ out)
{
    const int tid  = threadIdx.x;
    const int lane = tid & 63;
    const int wid  = blockIdx.x * 4 + (tid >> 6);  // 0..4095
    const int igrp = wid >> 7;                     // 0..31
    const int jseg = wid & 127;                    // 0..127
    const int row  = igrp * 64 + lane;             // 0..2047 (flat b*S+i)
    const int bidx = row >> 10;
    const int jr0  = (bidx << 10) + (jseg << 3);   // first of 8 hjb rows

    // A row resident in registers — STATIC indexing only (rule #20).
    float4 av[32];
    {
        const float4* ap = reinterpret_cast<const float4*>(hi + (size_t)row * DDIM);
        #pragma unroll
        for (int c = 0; c < 32; ++c) av[c] = ap[c];
    }

    // 4 accumulators per j (independent fma chains), seeded with si+sj.
    float acc[8][4];
    const float si = si2[row];
    #pragma unroll
    for (int jj = 0; jj < 8; ++jj) {
        acc[jj][0] = si + sj2[jr0 + jj];
        acc[jj][1] = 0.f; acc[jj][2] = 0.f; acc[jj][3] = 0.f;
    }

    // All B loads: one base pointer + immediate offsets (jj*512+c*16 <= 4080).
    const float4* bbase = reinterpret_cast<const float4*>(hjb + (size_t)jr0 * DDIM);
    const float4* wbase = reinterpret_cast<const float4*>(w2h);

    #pragma unroll
    for (int c = 0; c < 32; ++c) {
        const float4 W = wbase[c];
        const float4 A = av[c];
        #pragma unroll
        for (int jj = 0; jj < 8; ++jj) {
            const float4 B = bbase[jj * 32 + c];
            f2 t01 = (f2){A.x, A.y} + (f2){B.x, B.y};   // v_pk_add_f32
            f2 t23 = (f2){A.z, A.w} + (f2){B.z, B.w};   // v_pk_add_f32
            acc[jj][0] = fmaf(fabsf(t01.x), W.x, acc[jj][0]);  // abs = src mod
            acc[jj][1] = fmaf(fabsf(t01.y), W.y, acc[jj][1]);
            acc[jj][2] = fmaf(fabsf(t23.x), W.z, acc[jj][2]);
            acc[jj][3] = fmaf(fabsf(t23.y), W.w, acc[jj][3]);
        }
    }

    float res[8];
    #pragma unroll
    for (int jj = 0; jj < 8; ++jj)
        res[jj] = (acc[jj][0] + acc[jj][1]) + (acc[jj][2] + acc[jj][3]);

    float* op = out + (size_t)row * SDIM + (jseg << 3);
    reinterpret_cast<float4*>(op)[0] = make_float4(res[0], res[1], res[2], res[3]);
    reinterpret_cast<float4*>(op)[1] = make_float4(res[4], res[5], res[6], res[7]);
}

extern "C" void kernel_launch(void* const* d_in, const int* in_sizes, int n_in,
                              void* d_out, int out_size, void* d_ws, size_t ws_size,
                              hipStream_t stream) {
    const float* x  = (const float*)d_in[0];
    const float* W1 = (const float*)d_in[1];
    const float* b1 = (const float*)d_in[2];
    const float* W2 = (const float*)d_in[3];
    const float* b2 = (const float*)d_in[4];
    float* out = (float*)d_out;

    float* ws  = (float*)d_ws;
    float* hi  = ws;                                    // B*S*D
    float* hjb = ws + (size_t)BB * SDIM * DDIM;         // B*S*D
    float* si2 = ws + (size_t)2 * BB * SDIM * DDIM;     // B*S
    float* sj2 = si2 + (size_t)BB * SDIM;               // B*S
    float* w2h = sj2 + (size_t)BB * SDIM;               // D

    proj_kernel<<<BB * SDIM / K1_ROWS, 256, 0, stream>>>(x, W1, b1, W2, b2, hi, hjb, si2, sj2, w2h);
    edge_kernel<<<SDIM * SDIM * BB / (64 * 8 * 4), 256, 0, stream>>>(hi, hjb, si2, sj2, w2h, out);
}